// Round 1
// baseline (446.521 us; speedup 1.0000x reference)
//
#include <hip/hip_runtime.h>

// LinearAttention fused pipeline for MI355X (gfx950).
// b=32, C=128, n=4096, H=4 heads, D=32 head-dim.
//
// K1: kv projection (bf16 MFMA) + exp(k) + ctx/Z partial accumulation (atomics)
// K2: q projection (MFMA) + softmax_d + attn + Wo projection (MFMA) + stats
// K3: GroupNorm normalization in place on d_out.
//
// ws layout (fp32): ctx_u[32][4][32][32] | Z[32][128] | stats[32][2]  (~541 KB)

#define B_   32
#define C_   128
#define N_   4096
#define H_   4
#define D_   32
#define HID  128
#define NB   64            // columns per block tile
#define NTL  (N_ / NB)     // 64 tiles
#define STA  136           // LDS row stride (shorts) for xT/attnT rows (128 cols + pad, 16B-aligned)
#define STO  72            // LDS row stride (shorts) for expk/v/q rows (64 cols + pad, 16B-aligned)
#define SCALE 0.1767766952966369f
#define EPS  1e-5f

typedef __attribute__((ext_vector_type(8))) short short8;
typedef __attribute__((ext_vector_type(4))) short short4v;
typedef __attribute__((ext_vector_type(4))) float floatx4;

__device__ __forceinline__ short f2bf(float f) {   // RNE fp32 -> bf16
  unsigned u = __float_as_uint(f);
  u += 0x7FFFu + ((u >> 16) & 1u);
  return (short)(u >> 16);
}
__device__ __forceinline__ float bf2f(short h) {
  return __uint_as_float(((unsigned)(unsigned short)h) << 16);
}

// ---------------------------------------------------------------- K1
__global__ __launch_bounds__(256) void k_kv_ctx(
    const float* __restrict__ x, const float* __restrict__ Wk,
    const float* __restrict__ Wv, float* __restrict__ ctx_u,
    float* __restrict__ Zsum) {
  __shared__ short lds0[HID * STO];  // phase 1: xT[n][c] (stride STA, 64 rows); phase 2: expk[o][n]
  __shared__ short lds1[HID * STO];  // v[o][n]
  const int tid = threadIdx.x;
  const int w = tid >> 6, L = tid & 63, l15 = L & 15, q4 = L >> 4;
  const int b = blockIdx.x >> 6;
  const int n0 = (blockIdx.x & 63) * NB;
  const float* xb = x + (size_t)b * C_ * N_ + n0;

  // stage x^T as bf16: xT[n][c]
  {
    const int nl = tid & 63, cg = tid >> 6;
    for (int it = 0; it < 8; ++it) {
      const int c = it * 16 + cg * 4;
      float f0 = xb[(size_t)(c + 0) * N_ + nl];
      float f1 = xb[(size_t)(c + 1) * N_ + nl];
      float f2 = xb[(size_t)(c + 2) * N_ + nl];
      float f3 = xb[(size_t)(c + 3) * N_ + nl];
      short4v pk = { f2bf(f0), f2bf(f1), f2bf(f2), f2bf(f3) };
      *(short4v*)&lds0[nl * STA + c] = pk;
    }
  }
  __syncthreads();

  floatx4 acc[2][4];
  short8 af[2][4];
  const floatx4 z4 = {0.f, 0.f, 0.f, 0.f};

  for (int which = 0; which < 2; ++which) {   // 0 = v, 1 = k
    const float* W = which ? Wk : Wv;
#pragma unroll
    for (int mt = 0; mt < 2; ++mt)
#pragma unroll
      for (int ks = 0; ks < 4; ++ks) {
        const floatx4* p = (const floatx4*)&W[(size_t)(w * 32 + mt * 16 + l15) * C_ + ks * 32 + q4 * 8];
        floatx4 u0 = p[0], u1 = p[1];
        short8 a8;
        a8[0] = f2bf(u0[0]); a8[1] = f2bf(u0[1]); a8[2] = f2bf(u0[2]); a8[3] = f2bf(u0[3]);
        a8[4] = f2bf(u1[0]); a8[5] = f2bf(u1[1]); a8[6] = f2bf(u1[2]); a8[7] = f2bf(u1[3]);
        af[mt][ks] = a8;
      }
#pragma unroll
    for (int mt = 0; mt < 2; ++mt)
#pragma unroll
      for (int nt = 0; nt < 4; ++nt) acc[mt][nt] = z4;
#pragma unroll
    for (int ks = 0; ks < 4; ++ks) {
      short8 bf8[4];
#pragma unroll
      for (int nt = 0; nt < 4; ++nt)
        bf8[nt] = *(const short8*)&lds0[(nt * 16 + l15) * STA + ks * 32 + q4 * 8];
#pragma unroll
      for (int mt = 0; mt < 2; ++mt)
#pragma unroll
        for (int nt = 0; nt < 4; ++nt)
          acc[mt][nt] = __builtin_amdgcn_mfma_f32_16x16x32_bf16(af[mt][ks], bf8[nt], acc[mt][nt], 0, 0, 0);
    }
    if (which == 0) {
      // v -> lds1 (C/D layout: row = mt*16 + q4*4 + r, col = nt*16 + l15)
#pragma unroll
      for (int mt = 0; mt < 2; ++mt)
#pragma unroll
        for (int nt = 0; nt < 4; ++nt)
#pragma unroll
          for (int r = 0; r < 4; ++r)
            lds1[(w * 32 + mt * 16 + q4 * 4 + r) * STO + nt * 16 + l15] = f2bf(acc[mt][nt][r]);
    } else {
#pragma unroll
      for (int mt = 0; mt < 2; ++mt)
#pragma unroll
        for (int nt = 0; nt < 4; ++nt)
#pragma unroll
          for (int r = 0; r < 4; ++r)
            acc[mt][nt][r] = __expf(acc[mt][nt][r]);
      __syncthreads();   // all waves done reading xT before overwrite
#pragma unroll
      for (int mt = 0; mt < 2; ++mt)
#pragma unroll
        for (int nt = 0; nt < 4; ++nt)
#pragma unroll
          for (int r = 0; r < 4; ++r)
            lds0[(w * 32 + mt * 16 + q4 * 4 + r) * STO + nt * 16 + l15] = f2bf(acc[mt][nt][r]);
    }
  }
  __syncthreads();

  // Z partials: row sums of expk over this tile's 64 columns
  if (tid < HID) {
    float s = 0.f;
#pragma unroll
    for (int n8 = 0; n8 < NB; n8 += 8) {
      short8 r8 = *(const short8*)&lds0[tid * STO + n8];
#pragma unroll
      for (int j = 0; j < 8; ++j) s += bf2f(r8[j]);
    }
    atomicAdd(&Zsum[b * HID + tid], s);
  }

  // ctx partials: ctx_u[h][d][e] += sum_n expk[h*32+d][n] * v[h*32+e][n]
  {
    const int h = tid >> 6, t6 = tid & 63;
    const int d0 = (t6 >> 3) * 4, e0 = (t6 & 7) * 4;
    float a[4][4] = {};
    for (int n8 = 0; n8 < NB; n8 += 8) {
      float kf[4][8], vf[4][8];
#pragma unroll
      for (int i = 0; i < 4; ++i) {
        short8 kr = *(const short8*)&lds0[(h * 32 + d0 + i) * STO + n8];
        short8 vr = *(const short8*)&lds1[(h * 32 + e0 + i) * STO + n8];
#pragma unroll
        for (int j = 0; j < 8; ++j) { kf[i][j] = bf2f(kr[j]); vf[i][j] = bf2f(vr[j]); }
      }
#pragma unroll
      for (int i = 0; i < 4; ++i)
#pragma unroll
        for (int j = 0; j < 4; ++j) {
          float s = a[i][j];
#pragma unroll
          for (int u = 0; u < 8; ++u) s += kf[i][u] * vf[j][u];
          a[i][j] = s;
        }
    }
    float* cb = &ctx_u[(((size_t)b * H_ + h) * D_ + d0) * D_ + e0];
#pragma unroll
    for (int i = 0; i < 4; ++i)
#pragma unroll
      for (int j = 0; j < 4; ++j)
        atomicAdd(&cb[i * D_ + j], a[i][j]);
  }
}

// ---------------------------------------------------------------- K2
__global__ __launch_bounds__(256) void k_q_attn_o(
    const float* __restrict__ x, const float* __restrict__ Wq,
    const float* __restrict__ Wo, const float* __restrict__ bo,
    const float* __restrict__ ctx_u, const float* __restrict__ Zsum,
    float* __restrict__ outp, float* __restrict__ stats) {
  __shared__ short s_xa[NB * STA];      // xT[n][c] then attnT[n][o]
  __shared__ short s_q[HID * STO];      // q[o][n]
  __shared__ float s_ctx[H_ * D_ * D_]; // finalized ctx
  const int tid = threadIdx.x;
  const int w = tid >> 6, L = tid & 63, l15 = L & 15, q4 = L >> 4;
  const int b = blockIdx.x >> 6;
  const int n0 = (blockIdx.x & 63) * NB;
  const float* xb = x + (size_t)b * C_ * N_ + n0;

  // finalize ctx = ctx_u / Z into LDS
#pragma unroll
  for (int i = 0; i < 16; ++i) {
    int idx = tid + i * 256;  // 0..4095 = h*1024 + d*32 + e
    s_ctx[idx] = ctx_u[(size_t)b * (H_ * D_ * D_) + idx] / Zsum[b * HID + (idx >> 5)];
  }
  // stage x^T
  {
    const int nl = tid & 63, cg = tid >> 6;
    for (int it = 0; it < 8; ++it) {
      const int c = it * 16 + cg * 4;
      float f0 = xb[(size_t)(c + 0) * N_ + nl];
      float f1 = xb[(size_t)(c + 1) * N_ + nl];
      float f2 = xb[(size_t)(c + 2) * N_ + nl];
      float f3 = xb[(size_t)(c + 3) * N_ + nl];
      short4v pk = { f2bf(f0), f2bf(f1), f2bf(f2), f2bf(f3) };
      *(short4v*)&s_xa[nl * STA + c] = pk;
    }
  }
  __syncthreads();

  floatx4 acc[2][4];
  short8 af[2][4];
  const floatx4 z4 = {0.f, 0.f, 0.f, 0.f};

  // q = Wq @ x (wave w computes head w's 32 rows)
#pragma unroll
  for (int mt = 0; mt < 2; ++mt)
#pragma unroll
    for (int ks = 0; ks < 4; ++ks) {
      const floatx4* p = (const floatx4*)&Wq[(size_t)(w * 32 + mt * 16 + l15) * C_ + ks * 32 + q4 * 8];
      floatx4 u0 = p[0], u1 = p[1];
      short8 a8;
      a8[0] = f2bf(u0[0]); a8[1] = f2bf(u0[1]); a8[2] = f2bf(u0[2]); a8[3] = f2bf(u0[3]);
      a8[4] = f2bf(u1[0]); a8[5] = f2bf(u1[1]); a8[6] = f2bf(u1[2]); a8[7] = f2bf(u1[3]);
      af[mt][ks] = a8;
    }
#pragma unroll
  for (int mt = 0; mt < 2; ++mt)
#pragma unroll
    for (int nt = 0; nt < 4; ++nt) acc[mt][nt] = z4;
#pragma unroll
  for (int ks = 0; ks < 4; ++ks) {
    short8 bf8[4];
#pragma unroll
    for (int nt = 0; nt < 4; ++nt)
      bf8[nt] = *(const short8*)&s_xa[(nt * 16 + l15) * STA + ks * 32 + q4 * 8];
#pragma unroll
    for (int mt = 0; mt < 2; ++mt)
#pragma unroll
      for (int nt = 0; nt < 4; ++nt)
        acc[mt][nt] = __builtin_amdgcn_mfma_f32_16x16x32_bf16(af[mt][ks], bf8[nt], acc[mt][nt], 0, 0, 0);
  }
#pragma unroll
  for (int mt = 0; mt < 2; ++mt)
#pragma unroll
    for (int nt = 0; nt < 4; ++nt)
#pragma unroll
      for (int r = 0; r < 4; ++r)
        s_q[(w * 32 + mt * 16 + q4 * 4 + r) * STO + nt * 16 + l15] = f2bf(acc[mt][nt][r]);
  __syncthreads();

  // softmax over d (+SCALE) and attn: one thread per (head=w, column n)
  {
    const int n = tid & 63;
    float qs[32];
    float ssum = 0.f;
#pragma unroll
    for (int d = 0; d < 32; ++d) {
      float e = __expf(bf2f(s_q[(w * 32 + d) * STO + n]));
      qs[d] = e; ssum += e;
    }
    const float inv = SCALE / ssum;
    float ov[32];
#pragma unroll
    for (int e = 0; e < 32; ++e) ov[e] = 0.f;
    const float* cxh = &s_ctx[w * (D_ * D_)];
    for (int d = 0; d < 32; ++d) {
      const float qd = qs[d] * inv;
      const floatx4* cr = (const floatx4*)&cxh[d * D_];
#pragma unroll
      for (int e4 = 0; e4 < 8; ++e4) {
        floatx4 c4 = cr[e4];
        ov[e4 * 4 + 0] += c4[0] * qd; ov[e4 * 4 + 1] += c4[1] * qd;
        ov[e4 * 4 + 2] += c4[2] * qd; ov[e4 * 4 + 3] += c4[3] * qd;
      }
    }
    // attnT[n][h*32+e] over the dead xT region (xT reads all finished at last barrier)
#pragma unroll
    for (int e4 = 0; e4 < 8; ++e4) {
      short4v pk = { f2bf(ov[e4 * 4 + 0]), f2bf(ov[e4 * 4 + 1]),
                     f2bf(ov[e4 * 4 + 2]), f2bf(ov[e4 * 4 + 3]) };
      *(short4v*)&s_xa[n * STA + w * 32 + e4 * 4] = pk;
    }
  }
  __syncthreads();

  // out_pre = Wo @ attn + bo
#pragma unroll
  for (int mt = 0; mt < 2; ++mt)
#pragma unroll
    for (int ks = 0; ks < 4; ++ks) {
      const floatx4* p = (const floatx4*)&Wo[(size_t)(w * 32 + mt * 16 + l15) * HID + ks * 32 + q4 * 8];
      floatx4 u0 = p[0], u1 = p[1];
      short8 a8;
      a8[0] = f2bf(u0[0]); a8[1] = f2bf(u0[1]); a8[2] = f2bf(u0[2]); a8[3] = f2bf(u0[3]);
      a8[4] = f2bf(u1[0]); a8[5] = f2bf(u1[1]); a8[6] = f2bf(u1[2]); a8[7] = f2bf(u1[3]);
      af[mt][ks] = a8;
    }
#pragma unroll
  for (int mt = 0; mt < 2; ++mt)
#pragma unroll
    for (int nt = 0; nt < 4; ++nt) acc[mt][nt] = z4;
#pragma unroll
  for (int ks = 0; ks < 4; ++ks) {
    short8 bf8[4];
#pragma unroll
    for (int nt = 0; nt < 4; ++nt)
      bf8[nt] = *(const short8*)&s_xa[(nt * 16 + l15) * STA + ks * 32 + q4 * 8];
#pragma unroll
    for (int mt = 0; mt < 2; ++mt)
#pragma unroll
      for (int nt = 0; nt < 4; ++nt)
        acc[mt][nt] = __builtin_amdgcn_mfma_f32_16x16x32_bf16(af[mt][ks], bf8[nt], acc[mt][nt], 0, 0, 0);
  }

  // epilogue: +bo, store, per-batch stats
  float s1 = 0.f, s2 = 0.f;
#pragma unroll
  for (int mt = 0; mt < 2; ++mt) {
    const int rowbase = w * 32 + mt * 16 + q4 * 4;
    const floatx4 bo4 = *(const floatx4*)&bo[rowbase];
#pragma unroll
    for (int nt = 0; nt < 4; ++nt) {
      const int n = n0 + nt * 16 + l15;
#pragma unroll
      for (int r = 0; r < 4; ++r) {
        float vv = acc[mt][nt][r] + bo4[r];
        outp[(size_t)b * (C_ * N_) + (size_t)(rowbase + r) * N_ + n] = vv;
        s1 += vv; s2 += vv * vv;
      }
    }
  }
#pragma unroll
  for (int m = 1; m < 64; m <<= 1) {
    s1 += __shfl_xor(s1, m);
    s2 += __shfl_xor(s2, m);
  }
  if (L == 0) {
    atomicAdd(&stats[b * 2 + 0], s1);
    atomicAdd(&stats[b * 2 + 1], s2);
  }
}

// ---------------------------------------------------------------- K3
__global__ __launch_bounds__(256) void k_gnorm(
    float* __restrict__ outp, const float* __restrict__ stats,
    const float* __restrict__ gnw, const float* __restrict__ gnb) {
  const int b = blockIdx.x >> 6;
  const int blk = blockIdx.x & 63;
  const float M = (float)(C_ * N_);
  const float mu = stats[b * 2 + 0] / M;
  const float var = stats[b * 2 + 1] / M - mu * mu;
  const float rs = rsqrtf(var + EPS);
  floatx4* p = (floatx4*)(outp + (size_t)b * (C_ * N_) + (size_t)blk * 8192);
  const int tid = threadIdx.x;
#pragma unroll
  for (int i = 0; i < 8; ++i) {
    const int idx = tid + i * 256;            // 0..2047 float4s
    const int fl = blk * 8192 + idx * 4;      // flat offset within sample
    const int c = fl >> 12;                   // channel (4096 elems per channel)
    const float wgt = gnw[c] * rs;
    const float bia = gnb[c] - mu * wgt;
    floatx4 v = p[idx];
    v[0] = v[0] * wgt + bia;
    v[1] = v[1] * wgt + bia;
    v[2] = v[2] * wgt + bia;
    v[3] = v[3] * wgt + bia;
    p[idx] = v;
  }
}

// ---------------------------------------------------------------- launch
extern "C" void kernel_launch(void* const* d_in, const int* in_sizes, int n_in,
                              void* d_out, int out_size, void* d_ws, size_t ws_size,
                              hipStream_t stream) {
  (void)in_sizes; (void)n_in; (void)out_size; (void)ws_size;
  const float* x   = (const float*)d_in[0];
  const float* Wq  = (const float*)d_in[1];
  const float* Wk  = (const float*)d_in[2];
  const float* Wv  = (const float*)d_in[3];
  const float* Wo  = (const float*)d_in[4];
  const float* bo  = (const float*)d_in[5];
  const float* gnw = (const float*)d_in[6];
  const float* gnb = (const float*)d_in[7];
  float* outp  = (float*)d_out;
  float* ctx_u = (float*)d_ws;                       // 32*4*32*32 = 131072 floats
  float* Zsum  = ctx_u + B_ * H_ * D_ * D_;          // 32*128 = 4096 floats
  float* stats = Zsum + B_ * HID;                    // 32*2 = 64 floats
  const size_t zbytes = (size_t)(B_ * H_ * D_ * D_ + B_ * HID + B_ * 2) * sizeof(float);
  hipMemsetAsync(d_ws, 0, zbytes, stream);
  hipLaunchKernelGGL(k_kv_ctx,   dim3(B_ * NTL), dim3(256), 0, stream, x, Wk, Wv, ctx_u, Zsum);
  hipLaunchKernelGGL(k_q_attn_o, dim3(B_ * NTL), dim3(256), 0, stream, x, Wq, Wo, bo, ctx_u, Zsum, outp, stats);
  hipLaunchKernelGGL(k_gnorm,    dim3(B_ * 64),  dim3(256), 0, stream, outp, stats, gnw, gnb);
}

// Round 2
// 306.701 us; speedup vs baseline: 1.4559x; 1.4559x over previous
//
#include <hip/hip_runtime.h>

// LinearAttention fused pipeline for MI355X (gfx950) — round 2.
// All einsums on MFMA; weights pre-cast to bf16 once (K0).
// b=32, C=128, n=4096, H=4 heads, D=32 head-dim.
//
// ws layout: ctx_u[32][4][32][32] f32 | Z[32][128] f32 | stats[32][2] f32 |
//            Wq_bf Wk_bf Wv_bf Wo_bf (4 x 16384 bf16)   (~656 KB total)

#define B_   32
#define C_   128
#define N_   4096
#define H_   4
#define D_   32
#define HID  128
#define NB   64
#define STA  136      // xT/qT/attnT row stride (shorts): 128 cols + pad, 16B-aligned rows
#define STV  72       // v/ek row stride (shorts): 64 cols + pad, 16B-aligned rows
#define SCT  40       // ctxT row stride (shorts): 32 cols + pad, 16B-aligned rows
#define SCALE 0.1767766952966369f
#define EPS  1e-5f

typedef __attribute__((ext_vector_type(8))) short short8;
typedef __attribute__((ext_vector_type(4))) short short4v;
typedef __attribute__((ext_vector_type(4))) float floatx4;

__device__ __forceinline__ short f2bf(float f) {   // RNE fp32 -> bf16
  unsigned u = __float_as_uint(f);
  u += 0x7FFFu + ((u >> 16) & 1u);
  return (short)(u >> 16);
}
__device__ __forceinline__ float bf2f(short h) {
  return __uint_as_float(((unsigned)(unsigned short)h) << 16);
}

// ---------------------------------------------------------------- K0: weights -> bf16
__global__ __launch_bounds__(256) void k_wcast(
    const float* __restrict__ Wq, const float* __restrict__ Wk,
    const float* __restrict__ Wv, const float* __restrict__ Wo,
    short* __restrict__ wb) {
  const int i = blockIdx.x * 256 + threadIdx.x;   // 0..16383, 4 elems each
  const float* srcs[4] = {Wq, Wk, Wv, Wo};
#pragma unroll
  for (int m = 0; m < 4; ++m) {
    floatx4 a = ((const floatx4*)srcs[m])[i];
    short4v s = { f2bf(a[0]), f2bf(a[1]), f2bf(a[2]), f2bf(a[3]) };
    ((short4v*)(wb + m * 16384))[i] = s;
  }
}

// ---------------------------------------------------------------- K1: k,v proj + ctx/Z
__global__ __launch_bounds__(256, 4) void k_kv_ctx(
    const float* __restrict__ x, const short* __restrict__ Wkb,
    const short* __restrict__ Wvb, float* __restrict__ ctx_u,
    float* __restrict__ Zsum) {
  __shared__ short bufA[9216];        // xT[64][STA] -> ek[128][STV]
  __shared__ short bufV[HID * STV];   // v[128][STV]
  const int tid = threadIdx.x;
  const int w = tid >> 6, l15 = tid & 15, q4 = (tid & 63) >> 4;
  const int b = blockIdx.x >> 6;
  const int n0 = (blockIdx.x & 63) * NB;
  const float* xb = x + (size_t)b * C_ * N_ + n0;

  // stage xT[n][c] bf16
  {
    const int nl = tid & 63, cg = tid >> 6;
    for (int it = 0; it < 8; ++it) {
      const int c = it * 16 + cg * 4;
      float f0 = xb[(size_t)(c + 0) * N_ + nl];
      float f1 = xb[(size_t)(c + 1) * N_ + nl];
      float f2 = xb[(size_t)(c + 2) * N_ + nl];
      float f3 = xb[(size_t)(c + 3) * N_ + nl];
      short4v pk = { f2bf(f0), f2bf(f1), f2bf(f2), f2bf(f3) };
      *(short4v*)&bufA[nl * STA + c] = pk;
    }
  }
  __syncthreads();

  const floatx4 z4 = {0.f, 0.f, 0.f, 0.f};
  floatx4 acc[2][4];
  short8 af[2][4];

  // ---- v = Wv @ x  (wave w -> head rows [32w,32w+32))
#pragma unroll
  for (int mt = 0; mt < 2; ++mt)
#pragma unroll
    for (int ks = 0; ks < 4; ++ks)
      af[mt][ks] = *(const short8*)&Wvb[(w * 32 + mt * 16 + l15) * C_ + ks * 32 + q4 * 8];
#pragma unroll
  for (int mt = 0; mt < 2; ++mt)
#pragma unroll
    for (int nt = 0; nt < 4; ++nt) acc[mt][nt] = z4;
#pragma unroll
  for (int ks = 0; ks < 4; ++ks) {
    short8 bf8[4];
#pragma unroll
    for (int nt = 0; nt < 4; ++nt)
      bf8[nt] = *(const short8*)&bufA[(nt * 16 + l15) * STA + ks * 32 + q4 * 8];
#pragma unroll
    for (int mt = 0; mt < 2; ++mt)
#pragma unroll
      for (int nt = 0; nt < 4; ++nt)
        acc[mt][nt] = __builtin_amdgcn_mfma_f32_16x16x32_bf16(af[mt][ks], bf8[nt], acc[mt][nt], 0, 0, 0);
  }
  // write v[o][n] (wave-local rows)
#pragma unroll
  for (int mt = 0; mt < 2; ++mt)
#pragma unroll
    for (int nt = 0; nt < 4; ++nt)
#pragma unroll
      for (int r = 0; r < 4; ++r)
        bufV[(w * 32 + mt * 16 + q4 * 4 + r) * STV + nt * 16 + l15] = f2bf(acc[mt][nt][r]);

  // ---- k = Wk @ x, then exp
#pragma unroll
  for (int mt = 0; mt < 2; ++mt)
#pragma unroll
    for (int ks = 0; ks < 4; ++ks)
      af[mt][ks] = *(const short8*)&Wkb[(w * 32 + mt * 16 + l15) * C_ + ks * 32 + q4 * 8];
#pragma unroll
  for (int mt = 0; mt < 2; ++mt)
#pragma unroll
    for (int nt = 0; nt < 4; ++nt) acc[mt][nt] = z4;
#pragma unroll
  for (int ks = 0; ks < 4; ++ks) {
    short8 bf8[4];
#pragma unroll
    for (int nt = 0; nt < 4; ++nt)
      bf8[nt] = *(const short8*)&bufA[(nt * 16 + l15) * STA + ks * 32 + q4 * 8];
#pragma unroll
    for (int mt = 0; mt < 2; ++mt)
#pragma unroll
      for (int nt = 0; nt < 4; ++nt)
        acc[mt][nt] = __builtin_amdgcn_mfma_f32_16x16x32_bf16(af[mt][ks], bf8[nt], acc[mt][nt], 0, 0, 0);
  }
#pragma unroll
  for (int mt = 0; mt < 2; ++mt)
#pragma unroll
    for (int nt = 0; nt < 4; ++nt)
#pragma unroll
      for (int r = 0; r < 4; ++r)
        acc[mt][nt][r] = __expf(acc[mt][nt][r]);
  __syncthreads();   // all waves done reading xT
  // ek[o][n] overwrites bufA
#pragma unroll
  for (int mt = 0; mt < 2; ++mt)
#pragma unroll
    for (int nt = 0; nt < 4; ++nt)
#pragma unroll
      for (int r = 0; r < 4; ++r)
        bufA[(w * 32 + mt * 16 + q4 * 4 + r) * STV + nt * 16 + l15] = f2bf(acc[mt][nt][r]);
  __syncthreads();

  // Z partials: row sums of ek
  if (tid < HID) {
    float s = 0.f;
#pragma unroll
    for (int n8 = 0; n8 < NB; n8 += 8) {
      short8 r8 = *(const short8*)&bufA[tid * STV + n8];
#pragma unroll
      for (int j = 0; j < 8; ++j) s += bf2f(r8[j]);
    }
    atomicAdd(&Zsum[b * HID + tid], s);
  }

  // ctx partial via MFMA: ctx[d][e] += sum_n ek[d][n] * v[e][n]  (wave-local rows)
  {
    floatx4 ca[2][2] = {{z4, z4}, {z4, z4}};
#pragma unroll
    for (int ks = 0; ks < 2; ++ks) {
      short8 ae[2], be[2];
#pragma unroll
      for (int mt = 0; mt < 2; ++mt)
        ae[mt] = *(const short8*)&bufA[(w * 32 + mt * 16 + l15) * STV + ks * 32 + q4 * 8];
#pragma unroll
      for (int nt = 0; nt < 2; ++nt)
        be[nt] = *(const short8*)&bufV[(w * 32 + nt * 16 + l15) * STV + ks * 32 + q4 * 8];
#pragma unroll
      for (int mt = 0; mt < 2; ++mt)
#pragma unroll
        for (int nt = 0; nt < 2; ++nt)
          ca[mt][nt] = __builtin_amdgcn_mfma_f32_16x16x32_bf16(ae[mt], be[nt], ca[mt][nt], 0, 0, 0);
    }
    float* cb = &ctx_u[((size_t)b * H_ + w) * (D_ * D_)];
#pragma unroll
    for (int mt = 0; mt < 2; ++mt)
#pragma unroll
      for (int nt = 0; nt < 2; ++nt)
#pragma unroll
        for (int r = 0; r < 4; ++r)
          atomicAdd(&cb[(mt * 16 + q4 * 4 + r) * D_ + nt * 16 + l15], ca[mt][nt][r]);
  }
}

// ---------------------------------------------------------------- K2: q proj + attn + Wo + stats
__global__ __launch_bounds__(256, 4) void k_q_attn_o(
    const float* __restrict__ x, const short* __restrict__ Wqb,
    const short* __restrict__ Wob, const float* __restrict__ bo,
    const float* __restrict__ ctx_u, const float* __restrict__ Zsum,
    float* __restrict__ outp, float* __restrict__ stats) {
  __shared__ short bufA[NB * STA];    // xT -> qT -> attnT  ([64][STA], col dim = 128)
  __shared__ short ctxT[HID * SCT];   // ctxT[h*32+e][d] bf16
  __shared__ float s_rz[HID];
  __shared__ float s_inv[H_ * NB];
  const int tid = threadIdx.x;
  const int w = tid >> 6, l15 = tid & 15, q4 = (tid & 63) >> 4;
  const int b = blockIdx.x >> 6;
  const int n0 = (blockIdx.x & 63) * NB;
  const float* xb = x + (size_t)b * C_ * N_ + n0;

  if (tid < HID) s_rz[tid] = 1.0f / Zsum[b * HID + tid];

  // stage xT[n][c] bf16
  {
    const int nl = tid & 63, cg = tid >> 6;
    for (int it = 0; it < 8; ++it) {
      const int c = it * 16 + cg * 4;
      float f0 = xb[(size_t)(c + 0) * N_ + nl];
      float f1 = xb[(size_t)(c + 1) * N_ + nl];
      float f2 = xb[(size_t)(c + 2) * N_ + nl];
      float f3 = xb[(size_t)(c + 3) * N_ + nl];
      short4v pk = { f2bf(f0), f2bf(f1), f2bf(f2), f2bf(f3) };
      *(short4v*)&bufA[nl * STA + c] = pk;
    }
  }
  __syncthreads();   // b1: xT + s_rz visible

  // fill ctxT[e + 32h][d] = ctx_u[h,d,e] / Z[h*32+d]  (bf16)
#pragma unroll
  for (int i = 0; i < 16; ++i) {
    const int idx = tid + i * 256;     // h*1024 + d*32 + e
    float v = ctx_u[(size_t)b * (H_ * D_ * D_) + idx] * s_rz[idx >> 5];
    ctxT[((idx >> 10) * 32 + (idx & 31)) * SCT + ((idx >> 5) & 31)] = f2bf(v);
  }

  const floatx4 z4 = {0.f, 0.f, 0.f, 0.f};
  floatx4 acc[2][4];
  short8 af[2][4];

  // ---- q = Wq @ x
#pragma unroll
  for (int mt = 0; mt < 2; ++mt)
#pragma unroll
    for (int ks = 0; ks < 4; ++ks)
      af[mt][ks] = *(const short8*)&Wqb[(w * 32 + mt * 16 + l15) * C_ + ks * 32 + q4 * 8];
#pragma unroll
  for (int mt = 0; mt < 2; ++mt)
#pragma unroll
    for (int nt = 0; nt < 4; ++nt) acc[mt][nt] = z4;
#pragma unroll
  for (int ks = 0; ks < 4; ++ks) {
    short8 bf8[4];
#pragma unroll
    for (int nt = 0; nt < 4; ++nt)
      bf8[nt] = *(const short8*)&bufA[(nt * 16 + l15) * STA + ks * 32 + q4 * 8];
#pragma unroll
    for (int mt = 0; mt < 2; ++mt)
#pragma unroll
      for (int nt = 0; nt < 4; ++nt)
        acc[mt][nt] = __builtin_amdgcn_mfma_f32_16x16x32_bf16(af[mt][ks], bf8[nt], acc[mt][nt], 0, 0, 0);
  }
#pragma unroll
  for (int mt = 0; mt < 2; ++mt)
#pragma unroll
    for (int nt = 0; nt < 4; ++nt)
#pragma unroll
      for (int r = 0; r < 4; ++r)
        acc[mt][nt][r] = __expf(acc[mt][nt][r]);
  __syncthreads();   // b2: all waves done reading xT; ctxT visible

  // write expq^T into bufA: qT[n][h*32+d], packed b64 (wave-column-disjoint)
#pragma unroll
  for (int mt = 0; mt < 2; ++mt)
#pragma unroll
    for (int nt = 0; nt < 4; ++nt) {
      short4v pk = { f2bf(acc[mt][nt][0]), f2bf(acc[mt][nt][1]),
                     f2bf(acc[mt][nt][2]), f2bf(acc[mt][nt][3]) };
      *(short4v*)&bufA[(nt * 16 + l15) * STA + w * 32 + mt * 16 + q4 * 4] = pk;
    }

  // column sums over d (wave-local: wave w reads only cols [32w,32w+32))
  {
    const int n = tid & 63;
    float ssum = 0.f;
#pragma unroll
    for (int j8 = 0; j8 < 32; j8 += 8) {
      short8 r8 = *(const short8*)&bufA[n * STA + w * 32 + j8];
#pragma unroll
      for (int j = 0; j < 8; ++j) ssum += bf2f(r8[j]);
    }
    s_inv[w * 64 + n] = SCALE / ssum;
  }

  // attn: out[e][n] = (sum_d ctxT[e][d] * expq[d][n]) * inv[n]   (8 MFMAs, K=32)
  {
    floatx4 aacc[2][4];
#pragma unroll
    for (int mt = 0; mt < 2; ++mt)
#pragma unroll
      for (int nt = 0; nt < 4; ++nt) aacc[mt][nt] = z4;
    short8 ae[2];
#pragma unroll
    for (int mt = 0; mt < 2; ++mt)
      ae[mt] = *(const short8*)&ctxT[(w * 32 + mt * 16 + l15) * SCT + q4 * 8];
#pragma unroll
    for (int nt = 0; nt < 4; ++nt) {
      short8 bq = *(const short8*)&bufA[(nt * 16 + l15) * STA + w * 32 + q4 * 8];
#pragma unroll
      for (int mt = 0; mt < 2; ++mt)
        aacc[mt][nt] = __builtin_amdgcn_mfma_f32_16x16x32_bf16(ae[mt], bq, aacc[mt][nt], 0, 0, 0);
    }
    // scale by inv[n], write attnT[n][h*32+e] over qT (wave-column-disjoint)
#pragma unroll
    for (int nt = 0; nt < 4; ++nt) {
      const float iv = s_inv[w * 64 + nt * 16 + l15];
#pragma unroll
      for (int mt = 0; mt < 2; ++mt) {
        short4v pk = { f2bf(aacc[mt][nt][0] * iv), f2bf(aacc[mt][nt][1] * iv),
                       f2bf(aacc[mt][nt][2] * iv), f2bf(aacc[mt][nt][3] * iv) };
        *(short4v*)&bufA[(nt * 16 + l15) * STA + w * 32 + mt * 16 + q4 * 4] = pk;
      }
    }
  }
  __syncthreads();   // b3: attnT ready for all waves

  // ---- out_pre = Wo @ attn + bo
#pragma unroll
  for (int mt = 0; mt < 2; ++mt)
#pragma unroll
    for (int ks = 0; ks < 4; ++ks)
      af[mt][ks] = *(const short8*)&Wob[(w * 32 + mt * 16 + l15) * HID + ks * 32 + q4 * 8];
#pragma unroll
  for (int mt = 0; mt < 2; ++mt)
#pragma unroll
    for (int nt = 0; nt < 4; ++nt) acc[mt][nt] = z4;
#pragma unroll
  for (int ks = 0; ks < 4; ++ks) {
    short8 bf8[4];
#pragma unroll
    for (int nt = 0; nt < 4; ++nt)
      bf8[nt] = *(const short8*)&bufA[(nt * 16 + l15) * STA + ks * 32 + q4 * 8];
#pragma unroll
    for (int mt = 0; mt < 2; ++mt)
#pragma unroll
      for (int nt = 0; nt < 4; ++nt)
        acc[mt][nt] = __builtin_amdgcn_mfma_f32_16x16x32_bf16(af[mt][ks], bf8[nt], acc[mt][nt], 0, 0, 0);
  }

  // epilogue: +bo, store, per-batch stats
  float s1 = 0.f, s2 = 0.f;
#pragma unroll
  for (int mt = 0; mt < 2; ++mt) {
    const int rowbase = w * 32 + mt * 16 + q4 * 4;
    const floatx4 bo4 = *(const floatx4*)&bo[rowbase];
#pragma unroll
    for (int nt = 0; nt < 4; ++nt) {
      const int n = n0 + nt * 16 + l15;
#pragma unroll
      for (int r = 0; r < 4; ++r) {
        float vv = acc[mt][nt][r] + bo4[r];
        outp[(size_t)b * (C_ * N_) + (size_t)(rowbase + r) * N_ + n] = vv;
        s1 += vv; s2 += vv * vv;
      }
    }
  }
#pragma unroll
  for (int m = 1; m < 64; m <<= 1) {
    s1 += __shfl_xor(s1, m);
    s2 += __shfl_xor(s2, m);
  }
  if ((tid & 63) == 0) {
    atomicAdd(&stats[b * 2 + 0], s1);
    atomicAdd(&stats[b * 2 + 1], s2);
  }
}

// ---------------------------------------------------------------- K3: GroupNorm
__global__ __launch_bounds__(256) void k_gnorm(
    float* __restrict__ outp, const float* __restrict__ stats,
    const float* __restrict__ gnw, const float* __restrict__ gnb) {
  const int b = blockIdx.x >> 6;
  const int blk = blockIdx.x & 63;
  const float M = (float)(C_ * N_);
  const float mu = stats[b * 2 + 0] / M;
  const float var = stats[b * 2 + 1] / M - mu * mu;
  const float rs = rsqrtf(var + EPS);
  floatx4* p = (floatx4*)(outp + (size_t)b * (C_ * N_) + (size_t)blk * 8192);
  const int tid = threadIdx.x;
#pragma unroll
  for (int i = 0; i < 8; ++i) {
    const int idx = tid + i * 256;
    const int fl = blk * 8192 + idx * 4;
    const int c = fl >> 12;
    const float wgt = gnw[c] * rs;
    const float bia = gnb[c] - mu * wgt;
    floatx4 v = p[idx];
    v[0] = v[0] * wgt + bia;
    v[1] = v[1] * wgt + bia;
    v[2] = v[2] * wgt + bia;
    v[3] = v[3] * wgt + bia;
    p[idx] = v;
  }
}

// ---------------------------------------------------------------- launch
extern "C" void kernel_launch(void* const* d_in, const int* in_sizes, int n_in,
                              void* d_out, int out_size, void* d_ws, size_t ws_size,
                              hipStream_t stream) {
  (void)in_sizes; (void)n_in; (void)out_size; (void)ws_size;
  const float* x   = (const float*)d_in[0];
  const float* Wq  = (const float*)d_in[1];
  const float* Wk  = (const float*)d_in[2];
  const float* Wv  = (const float*)d_in[3];
  const float* Wo  = (const float*)d_in[4];
  const float* bo  = (const float*)d_in[5];
  const float* gnw = (const float*)d_in[6];
  const float* gnb = (const float*)d_in[7];
  float* outp  = (float*)d_out;
  float* ctx_u = (float*)d_ws;                       // 131072 f
  float* Zsum  = ctx_u + B_ * H_ * D_ * D_;          // 4096 f
  float* stats = Zsum + B_ * HID;                    // 64 f
  short* wb    = (short*)(stats + B_ * 2);           // 4 x 16384 bf16
  const size_t zbytes = (size_t)(B_ * H_ * D_ * D_ + B_ * HID + B_ * 2) * sizeof(float);
  hipMemsetAsync(d_ws, 0, zbytes, stream);
  hipLaunchKernelGGL(k_wcast,    dim3(64),       dim3(256), 0, stream, Wq, Wk, Wv, Wo, wb);
  hipLaunchKernelGGL(k_kv_ctx,   dim3(B_ * 64),  dim3(256), 0, stream, x, wb + 16384, wb + 32768, ctx_u, Zsum);
  hipLaunchKernelGGL(k_q_attn_o, dim3(B_ * 64),  dim3(256), 0, stream, x, wb, wb + 49152, bo, ctx_u, Zsum, outp, stats);
  hipLaunchKernelGGL(k_gnorm,    dim3(B_ * 64),  dim3(256), 0, stream, outp, stats, gnw, gnb);
}